// Round 8
// baseline (154.848 us; speedup 1.0000x reference)
//
#include <hip/hip_runtime.h>
#include <hip/hip_bf16.h>
#include <math.h>

#define NB   32768
#define NM   2048
#define NEMB 128
#define NK   8
#define TAU  0.3f
#define FLT_BIG 3.402823466e38f

typedef __attribute__((ext_vector_type(8))) short bf16x8;
typedef __attribute__((ext_vector_type(4))) float f32x4;

// tanh-form GELU: x * sigmoid(2*0.79788456*(x+0.044715 x^3)), branch-free.
__device__ __forceinline__ float gelu_tanh(float x) {
    const float x2 = x * x;
    const float u  = fmaf(0.044715f, x2, 1.0f);
    const float a  = x * u * (-2.3022082f);          // -2*0.79788456*log2(e)
    const float e  = __builtin_amdgcn_exp2f(a);      // exp(-2t)
    const float r  = __builtin_amdgcn_rcpf(e + 1.0f);
    return x * r;                                    // x * sigmoid(2t)
}
// f32 pair -> packed bf16 (RNE): (bf16(hi)<<16)|bf16(lo), 1 v_cvt_pk_bf16_f32
__device__ __forceinline__ unsigned pack2(float lo, float hi) {
    __hip_bfloat162 b = __float22bfloat162_rn(make_float2(lo, hi));
    return *reinterpret_cast<unsigned*>(&b);
}

// DPP helpers: quad_perm xor1=0xB1, xor2=0x4E, row_half_mirror=0x141, row_mirror=0x140
template<int CTRL>
__device__ __forceinline__ unsigned dpp_umin(unsigned v) {
    const unsigned t = (unsigned)__builtin_amdgcn_update_dpp(0, (int)v, CTRL, 0xF, 0xF, true);
    return v < t ? v : t;
}
template<int CTRL>
__device__ __forceinline__ float dpp_fadd(float v) {
    const float t = __int_as_float(__builtin_amdgcn_update_dpp(0, __float_as_int(v), CTRL, 0xF, 0xF, true));
    return v + t;
}

// exact top-8 extraction over the union of per-lane sorted lists.
template<int DEPTH>
__device__ __forceinline__ int extract8(float (&ld)[DEPTH], unsigned (&lp)[DEPTH],
                                        float (&td)[8], unsigned (&tp)[8], const int lane) {
    int pops = 0;
#pragma unroll
    for (int k = 0; k < 8; ++k) {
        const unsigned key = __float_as_uint(ld[0]);
        unsigned m = key;
        m = dpp_umin<0xB1>(m);  m = dpp_umin<0x4E>(m);
        m = dpp_umin<0x141>(m); m = dpp_umin<0x140>(m);
        { unsigned t = __shfl_xor(m, 16); m = m < t ? m : t;
          t = __shfl_xor(m, 32);          m = m < t ? m : t; }
        const unsigned long long mk = __ballot(key == m);
        const int src = __ffsll(mk) - 1;          // lowest lane holding the min
        td[k] = __uint_as_float(m);
        tp[k] = __shfl(lp[0], src);
        if (lane == src) {
#pragma unroll
            for (int j = 0; j < DEPTH - 1; ++j) { ld[j] = ld[j + 1]; lp[j] = lp[j + 1]; }
            ld[DEPTH - 1] = FLT_BIG;
            ++pops;
        }
    }
    return pops;
}

// ---------------------------------------------------------------------------
// Phase 1: top-8 + softmax, NO LDS, 256 thr = 4 waves = 4 rows/block,
// 32 waves/CU (launch_bounds(256,8), ~50 VGPR). Plain loads (L3 retention
// between replays). Per row writes 8 x {w_k (f32 bits), packed bf16 (x,y)}.
// ---------------------------------------------------------------------------
__global__ void __launch_bounds__(256, 8) knn_phase1(
    const float* __restrict__ Gl, const float* __restrict__ ancL,
    uint2* __restrict__ ws2)
{
    const int tid  = threadIdx.x;
    const int wave = tid >> 6;
    const int lane = tid & 63;
    const int row  = (blockIdx.x << 2) + wave;

    const float2 g = reinterpret_cast<const float2*>(Gl)[row];
    const f32x4* a4 = reinterpret_cast<const f32x4*>(ancL) + (size_t)row * (NM / 2);

    float    bd[3];
    unsigned bp[3];
#pragma unroll
    for (int i = 0; i < 3; ++i) { bd[i] = FLT_BIG; bp[i] = 0u; }

    auto ins3 = [&](float d, unsigned p) {
        const bool c0 = d < bd[0], c1 = d < bd[1], c2 = d < bd[2];
        const float n2 = __builtin_amdgcn_fmed3f(d, bd[1], bd[2]);
        const float n1 = __builtin_amdgcn_fmed3f(d, bd[0], bd[1]);
        const float n0 = fminf(d, bd[0]);
        bp[2] = c1 ? bp[1] : (c2 ? p : bp[2]);
        bp[1] = c0 ? bp[0] : (c1 ? p : bp[1]);
        bp[0] = c0 ? p : bp[0];
        bd[2] = n2; bd[1] = n1; bd[0] = n0;
    };

    f32x4 buf[3];
#pragma unroll
    for (int j = 0; j < 3; ++j) buf[j] = a4[j * 64 + lane];

#pragma unroll
    for (int it = 0; it < 16; ++it) {
        const int slot = it % 3;                 // static after full unroll
        const f32x4 v = buf[slot];
        if (it + 3 < 16) buf[slot] = a4[(it + 3) * 64 + lane];
        const float dx0 = v.x - g.x, dy0 = v.y - g.y;
        const float dx1 = v.z - g.x, dy1 = v.w - g.y;
        // bit-identical to numpy: no fma contraction
        const float d0 = __fadd_rn(__fmul_rn(dx0, dx0), __fmul_rn(dy0, dy0));
        const float d1 = __fadd_rn(__fmul_rn(dx1, dx1), __fmul_rn(dy1, dy1));
        ins3(d0, pack2(v.x, v.y));
        ins3(d1, pack2(v.z, v.w));
    }

    float    td[8];
    unsigned tp[8];
    const int pops = extract8<3>(bd, bp, td, tp, lane);

    // exactness fallback (P~1.4%/row): some lane had all 3 popped
    if (__ballot(pops == 3)) {
        float    fd[8];
        unsigned fp[8];
#pragma unroll
        for (int i = 0; i < 8; ++i) { fd[i] = FLT_BIG; fp[i] = 0u; }
        for (int it = 0; it < 16; ++it) {
            const f32x4 vv = a4[it * 64 + lane];
#pragma unroll
            for (int h = 0; h < 2; ++h) {
                const float ax = h ? vv.z : vv.x;
                const float ay = h ? vv.w : vv.y;
                const float ddx = ax - g.x, ddy = ay - g.y;
                const float d = __fadd_rn(__fmul_rn(ddx, ddx), __fmul_rn(ddy, ddy));
                if (d < fd[7]) {
                    const unsigned p = pack2(ax, ay);
#pragma unroll
                    for (int j = 7; j >= 1; --j) {
                        const bool s1 = fd[j - 1] > d;
                        const bool s2 = fd[j] > d;
                        const float    nd = s1 ? fd[j - 1] : (s2 ? d : fd[j]);
                        const unsigned np = s1 ? fp[j - 1] : (s2 ? p : fp[j]);
                        fd[j] = nd; fp[j] = np;
                    }
                    if (fd[0] > d) { fd[0] = d; fp[0] = p; }
                }
            }
        }
        (void)extract8<8>(fd, fp, td, tp, lane);
    }

    // softmax(d2/tau); lane k (k<8) keeps w_k and tp[k]
    const float mx = td[7];
    float ek[8], ssum = 0.f;
#pragma unroll
    for (int k = 0; k < 8; ++k) { ek[k] = __expf((td[k] - mx) * (1.0f / TAU)); ssum += ek[k]; }
    const float inv = 1.0f / ssum;
    float    wv = 0.f;
    unsigned pv = 0u;
#pragma unroll
    for (int k = 0; k < 8; ++k) {
        wv = (lane == k) ? ek[k] * inv : wv;
        pv = (lane == k) ? tp[k]       : pv;
    }
    if (lane < 8) ws2[(size_t)row * 8 + lane] = make_uint2(__float_as_uint(wv), pv);
}

// ---------------------------------------------------------------------------
// Phase 2: MLP + weighted combine. 512 thr = 8 waves = 8 rows/block.
// W2 bf16 in LDS (swizzled); pair-tile h1; mfma_f32_16x16x32_bf16;
// epilogue gelu * w with DPP 8-lane k-reduction. Identical to R7 phase 2,
// sourcing per-row (w, packed xy) from ws.
// ---------------------------------------------------------------------------
__global__ void __launch_bounds__(512, 6) mlp_phase2(
    const uint2* __restrict__ ws2,
    const float* __restrict__ W1, const float* __restrict__ b1,
    const float* __restrict__ W2, const float* __restrict__ b2,
    float* __restrict__ out)
{
    __shared__ uint4  w2s[2048];      // 128 rows x 16 slots bf16x8, 32 KB
    __shared__ uint4  h1s4[1024];     // 4 pairs x 16 k-rows x 16 slots, 16 KB
    __shared__ float4 b2s4[32];
    __shared__ float  wts[8][8];

    const int tid  = threadIdx.x;
    const int wave = tid >> 6;
    const int lane = tid & 63;
    const int pair = wave >> 1;
    const int half = wave & 1;
    const int rowbase = blockIdx.x << 3;
    const int row  = rowbase + wave;

    // stage W2 (f32 -> bf16, phys_slot = slot ^ (row&7))
    {
        const float4* w2f = reinterpret_cast<const float4*>(W2);
        for (int i = tid; i < 2048; i += 512) {
            const float4 lo = w2f[i * 2], hi = w2f[i * 2 + 1];
            uint4 u;
            u.x = pack2(lo.x, lo.y); u.y = pack2(lo.z, lo.w);
            u.z = pack2(hi.x, hi.y); u.w = pack2(hi.z, hi.w);
            w2s[(i & ~15) | ((i & 15) ^ ((i >> 4) & 7))] = u;
        }
        if (tid < 32) b2s4[tid] = reinterpret_cast<const float4*>(b2)[tid];
    }
    // single __syncthreads below covers all staging

    // per-row data: lanes read the 8 uint2 (lane&7 -> broadcast-friendly)
    const uint2 q = ws2[(size_t)row * 8 + (lane & 7)];
    if (lane < 8) wts[wave][lane] = __uint_as_float(q.x);

    // layer 1: lane owns e0=2*lane, e1=2*lane+1; write to pair tile
    const float4 w1v = reinterpret_cast<const float4*>(W1)[lane];
    const float2 b1v = reinterpret_cast<const float2*>(b1)[lane];
    unsigned* h1w = reinterpret_cast<unsigned*>(h1s4 + (pair << 8));
#pragma unroll
    for (int k = 0; k < 8; ++k) {
        const unsigned pk = (unsigned)__shfl((int)q.y, k);
        const float ax = __uint_as_float(pk << 16);          // bf16 -> f32 exact
        const float ay = __uint_as_float(pk & 0xFFFF0000u);
        const float x0 = fmaf(ax, w1v.x, fmaf(ay, w1v.y, b1v.x));
        const float x1 = fmaf(ax, w1v.z, fmaf(ay, w1v.w, b1v.y));
        const int r = (half << 3) + k;   // row in pair tile; swizzle key = r&7 = k
        h1w[(r << 6) + ((((lane >> 2) ^ k) << 2) | (lane & 3))] = pack2(gelu_tanh(x0), gelu_tanh(x1));
    }
    __syncthreads();

    // B fragments from pair tile: col n = lane&15 (0..7 even row, 8..15 odd)
    const uint4* h1b = h1s4 + (pair << 8);
    const int bslot = lane >> 4, bxor = lane & 7, brow = (lane & 15) * 16;
    bf16x8 bq0 = __builtin_bit_cast(bf16x8, h1b[brow + (( 0 + bslot) ^ bxor)]);
    bf16x8 bq1 = __builtin_bit_cast(bf16x8, h1b[brow + (( 4 + bslot) ^ bxor)]);
    bf16x8 bq2 = __builtin_bit_cast(bf16x8, h1b[brow + (( 8 + bslot) ^ bxor)]);
    bf16x8 bq3 = __builtin_bit_cast(bf16x8, h1b[brow + ((12 + bslot) ^ bxor)]);

    const float wsel = wts[(pair << 1) | ((lane >> 3) & 1)][lane & 7];

    // MFMA: this wave does f-tiles half*4 .. half*4+3 for BOTH rows
#pragma unroll 2
    for (int i = 0; i < 4; ++i) {
        const int ft = (half << 2) + i;
        const int arow = (ft * 16 + (lane & 15)) * 16;
        f32x4 acc = {0.f, 0.f, 0.f, 0.f};
        acc = __builtin_amdgcn_mfma_f32_16x16x32_bf16(
                  __builtin_bit_cast(bf16x8, w2s[arow + (( 0 + bslot) ^ bxor)]), bq0, acc, 0, 0, 0);
        acc = __builtin_amdgcn_mfma_f32_16x16x32_bf16(
                  __builtin_bit_cast(bf16x8, w2s[arow + (( 4 + bslot) ^ bxor)]), bq1, acc, 0, 0, 0);
        acc = __builtin_amdgcn_mfma_f32_16x16x32_bf16(
                  __builtin_bit_cast(bf16x8, w2s[arow + (( 8 + bslot) ^ bxor)]), bq2, acc, 0, 0, 0);
        acc = __builtin_amdgcn_mfma_f32_16x16x32_bf16(
                  __builtin_bit_cast(bf16x8, w2s[arow + ((12 + bslot) ^ bxor)]), bq3, acc, 0, 0, 0);

        // D: row f = ft*16 + (lane>>4)*4 + j, col = lane&15
        const float4 b2v = b2s4[ft * 4 + (lane >> 4)];
        float s0 = gelu_tanh(acc[0] + b2v.x) * wsel;
        float s1 = gelu_tanh(acc[1] + b2v.y) * wsel;
        float s2 = gelu_tanh(acc[2] + b2v.z) * wsel;
        float s3 = gelu_tanh(acc[3] + b2v.w) * wsel;
        s0 = dpp_fadd<0xB1>(s0); s0 = dpp_fadd<0x4E>(s0); s0 = dpp_fadd<0x141>(s0);
        s1 = dpp_fadd<0xB1>(s1); s1 = dpp_fadd<0x4E>(s1); s1 = dpp_fadd<0x141>(s1);
        s2 = dpp_fadd<0xB1>(s2); s2 = dpp_fadd<0x4E>(s2); s2 = dpp_fadd<0x141>(s2);
        s3 = dpp_fadd<0xB1>(s3); s3 = dpp_fadd<0x4E>(s3); s3 = dpp_fadd<0x141>(s3);
        if ((lane & 7) == 0) {
            const int which = (lane >> 3) & 1;   // 0 = row even, 1 = row odd
            const size_t ob = (size_t)(rowbase + (pair << 1) + which) * NEMB
                              + ft * 16 + ((lane >> 4) << 2);
            *reinterpret_cast<float4*>(&out[ob]) = make_float4(s0, s1, s2, s3);
        }
    }
}

extern "C" void kernel_launch(void* const* d_in, const int* in_sizes, int n_in,
                              void* d_out, int out_size, void* d_ws, size_t ws_size,
                              hipStream_t stream)
{
    const float* Gl  = (const float*)d_in[0];
    const float* anc = (const float*)d_in[1];
    const float* W1  = (const float*)d_in[2];
    const float* b1  = (const float*)d_in[3];
    const float* W2  = (const float*)d_in[4];
    const float* b2  = (const float*)d_in[5];
    float* outp = (float*)d_out;
    uint2* ws2  = (uint2*)d_ws;          // 32768 * 8 * 8 B = 2 MiB

    knn_phase1<<<NB / 4, 256, 0, stream>>>(Gl, anc, ws2);
    mlp_phase2<<<NB / 8, 512, 0, stream>>>(ws2, W1, b1, W2, b2, outp);
}

// Round 9
// 132.796 us; speedup vs baseline: 1.1661x; 1.1661x over previous
//
#include <hip/hip_runtime.h>
#include <hip/hip_bf16.h>
#include <math.h>

#define NB   32768
#define NM   2048
#define NEMB 128
#define NK   8
#define TAU  0.3f
#define FLT_BIG 3.402823466e38f

typedef __attribute__((ext_vector_type(8))) short bf16x8;
typedef __attribute__((ext_vector_type(4))) float f32x4;

// tanh-form GELU: x * sigmoid(2*0.79788456*(x+0.044715 x^3)), branch-free.
__device__ __forceinline__ float gelu_tanh(float x) {
    const float x2 = x * x;
    const float u  = fmaf(0.044715f, x2, 1.0f);
    const float a  = x * u * (-2.3022082f);          // -2*0.79788456*log2(e)
    const float e  = __builtin_amdgcn_exp2f(a);      // exp(-2t)
    const float r  = __builtin_amdgcn_rcpf(e + 1.0f);
    return x * r;                                    // x * sigmoid(2t)
}
// f32 pair -> packed bf16 (RNE): (bf16(hi)<<16)|bf16(lo), 1 v_cvt_pk_bf16_f32
__device__ __forceinline__ unsigned pack2(float lo, float hi) {
    __hip_bfloat162 b = __float22bfloat162_rn(make_float2(lo, hi));
    return *reinterpret_cast<unsigned*>(&b);
}

// DPP helpers: quad_perm xor1=0xB1, xor2=0x4E, row_half_mirror=0x141, row_mirror=0x140
template<int CTRL>
__device__ __forceinline__ unsigned dpp_umin(unsigned v) {
    const unsigned t = (unsigned)__builtin_amdgcn_update_dpp(0, (int)v, CTRL, 0xF, 0xF, true);
    return v < t ? v : t;
}
template<int CTRL>
__device__ __forceinline__ float dpp_fadd(float v) {
    const float t = __int_as_float(__builtin_amdgcn_update_dpp(0, __float_as_int(v), CTRL, 0xF, 0xF, true));
    return v + t;
}

// exact top-8 extraction over the union of per-lane sorted lists.
template<int DEPTH>
__device__ __forceinline__ int extract8(float (&ld)[DEPTH], unsigned (&lp)[DEPTH],
                                        float (&td)[8], unsigned (&tp)[8], const int lane) {
    int pops = 0;
#pragma unroll
    for (int k = 0; k < 8; ++k) {
        const unsigned key = __float_as_uint(ld[0]);
        unsigned m = key;
        m = dpp_umin<0xB1>(m);  m = dpp_umin<0x4E>(m);
        m = dpp_umin<0x141>(m); m = dpp_umin<0x140>(m);
        { unsigned t = __shfl_xor(m, 16); m = m < t ? m : t;
          t = __shfl_xor(m, 32);          m = m < t ? m : t; }
        const unsigned long long mk = __ballot(key == m);
        const int src = __ffsll(mk) - 1;          // lowest lane holding the min
        td[k] = __uint_as_float(m);
        tp[k] = __shfl(lp[0], src);
        if (lane == src) {
#pragma unroll
            for (int j = 0; j < DEPTH - 1; ++j) { ld[j] = ld[j + 1]; lp[j] = lp[j + 1]; }
            ld[DEPTH - 1] = FLT_BIG;
            ++pops;
        }
    }
    return pops;
}

// ---------------------------------------------------------------------------
// Fused kernel, 512 threads = 8 waves = 8 rows/block. (R7 structure; the only
// change vs R7 is PLAIN loads in the stream -- A/B vs nontemporal: R2 evidence
// showed plain loads let Infinity Cache serve ~half the 512MiB stream across
// graph replays, FETCH_SIZE 264MB.)
// Phase 1: 3-deep rolling prefetch, unconditional per-lane sorted top-3
//   (fmed3 + packed-bf16 payload), DPP-argmin extraction x8, full-rescan
//   fallback (P~1.4%/row).
// Phase 2: softmax weights -> layer1 tanh-GELU -> bf16 h1 pair tile (LDS,
//   swizzled) -> mfma_f32_16x16x32_bf16 (A=W2 bf16 LDS) -> fused epilogue
//   with DPP 8-lane k-reduction. Row-pairing: B cols 0..7 even row, 8..15 odd.
// ---------------------------------------------------------------------------
__global__ void __launch_bounds__(512, 6) fused_anchor_mlp(
    const float* __restrict__ Gl, const float* __restrict__ ancL,
    const float* __restrict__ W1, const float* __restrict__ b1,
    const float* __restrict__ W2, const float* __restrict__ b2,
    float* __restrict__ out)
{
    __shared__ uint4  w2s[2048];      // 128 rows x 16 slots bf16x8, 32 KB
    __shared__ uint4  h1s4[1024];     // 4 pairs x 16 k-rows x 16 slots, 16 KB
    __shared__ float4 b2s4[32];       // 512 B
    __shared__ float  wts[8][8];      // softmax weights per row

    const int tid  = threadIdx.x;
    const int wave = tid >> 6;
    const int lane = tid & 63;
    const int pair = wave >> 1;
    const int half = wave & 1;
    const int rowbase = blockIdx.x << 3;
    const int row  = rowbase + wave;

    // --- stage W2 (f32 -> bf16, phys_slot = slot ^ (row&7)) ---
    {
        const float4* w2f = reinterpret_cast<const float4*>(W2);
        for (int i = tid; i < 2048; i += 512) {
            const float4 lo = w2f[i * 2], hi = w2f[i * 2 + 1];
            uint4 u;
            u.x = pack2(lo.x, lo.y); u.y = pack2(lo.z, lo.w);
            u.z = pack2(hi.x, hi.y); u.w = pack2(hi.z, hi.w);
            w2s[(i & ~15) | ((i & 15) ^ ((i >> 4) & 7))] = u;
        }
        if (tid < 32) b2s4[tid] = reinterpret_cast<const float4*>(b2)[tid];
    }
    // single __syncthreads below (after h1 writes) covers all staging

    // --- phase 1: stream anchors, 3-deep rolling prefetch, top-3/lane ---
    const float2 g = reinterpret_cast<const float2*>(Gl)[row];
    const f32x4* a4 = reinterpret_cast<const f32x4*>(ancL) + (size_t)row * (NM / 2);

    float    bd[3];
    unsigned bp[3];
#pragma unroll
    for (int i = 0; i < 3; ++i) { bd[i] = FLT_BIG; bp[i] = 0u; }

    auto ins3 = [&](float d, unsigned p) {
        const bool c0 = d < bd[0], c1 = d < bd[1], c2 = d < bd[2];
        const float n2 = __builtin_amdgcn_fmed3f(d, bd[1], bd[2]);
        const float n1 = __builtin_amdgcn_fmed3f(d, bd[0], bd[1]);
        const float n0 = fminf(d, bd[0]);
        bp[2] = c1 ? bp[1] : (c2 ? p : bp[2]);
        bp[1] = c0 ? bp[0] : (c1 ? p : bp[1]);
        bp[0] = c0 ? p : bp[0];
        bd[2] = n2; bd[1] = n1; bd[0] = n0;
    };

    f32x4 buf[3];
#pragma unroll
    for (int j = 0; j < 3; ++j) buf[j] = a4[j * 64 + lane];

#pragma unroll
    for (int it = 0; it < 16; ++it) {
        const int slot = it % 3;                 // static after full unroll
        const f32x4 v = buf[slot];
        if (it + 3 < 16) buf[slot] = a4[(it + 3) * 64 + lane];
        const float dx0 = v.x - g.x, dy0 = v.y - g.y;
        const float dx1 = v.z - g.x, dy1 = v.w - g.y;
        // bit-identical to numpy: no fma contraction
        const float d0 = __fadd_rn(__fmul_rn(dx0, dx0), __fmul_rn(dy0, dy0));
        const float d1 = __fadd_rn(__fmul_rn(dx1, dx1), __fmul_rn(dy1, dy1));
        ins3(d0, pack2(v.x, v.y));
        ins3(d1, pack2(v.z, v.w));
    }

    // --- extraction: 8 rounds of DPP-argmin over lane heads ---
    float    td[8];
    unsigned tp[8];
    const int pops = extract8<3>(bd, bp, td, tp, lane);

    // --- exactness fallback (P~1.4%/row): some lane had all 3 popped ---
    if (__ballot(pops == 3)) {
        float    fd[8];
        unsigned fp[8];
#pragma unroll
        for (int i = 0; i < 8; ++i) { fd[i] = FLT_BIG; fp[i] = 0u; }
        for (int it = 0; it < 16; ++it) {
            const f32x4 vv = a4[it * 64 + lane];
#pragma unroll
            for (int h = 0; h < 2; ++h) {
                const float ax = h ? vv.z : vv.x;
                const float ay = h ? vv.w : vv.y;
                const float ddx = ax - g.x, ddy = ay - g.y;
                const float d = __fadd_rn(__fmul_rn(ddx, ddx), __fmul_rn(ddy, ddy));
                if (d < fd[7]) {
                    const unsigned p = pack2(ax, ay);
#pragma unroll
                    for (int j = 7; j >= 1; --j) {
                        const bool s1 = fd[j - 1] > d;
                        const bool s2 = fd[j] > d;
                        const float    nd = s1 ? fd[j - 1] : (s2 ? d : fd[j]);
                        const unsigned np = s1 ? fp[j - 1] : (s2 ? p : fp[j]);
                        fd[j] = nd; fp[j] = np;
                    }
                    if (fd[0] > d) { fd[0] = d; fp[0] = p; }
                }
            }
        }
        (void)extract8<8>(fd, fp, td, tp, lane);
    }

    // --- softmax(d2/tau); publish weights for the pair epilogue ---
    const float mx = td[7];
    float ek[8], ssum = 0.f;
#pragma unroll
    for (int k = 0; k < 8; ++k) { ek[k] = __expf((td[k] - mx) * (1.0f / TAU)); ssum += ek[k]; }
    const float inv = 1.0f / ssum;
    float wv = 0.f;
#pragma unroll
    for (int k = 0; k < 8; ++k) wv = (lane == k) ? ek[k] * inv : wv;
    if (lane < 8) wts[wave][lane] = wv;

    // --- layer 1: lane owns e0=2*lane, e1=2*lane+1; write to pair tile ---
    const float4 w1v = reinterpret_cast<const float4*>(W1)[lane];
    const float2 b1v = reinterpret_cast<const float2*>(b1)[lane];
    unsigned* h1w = reinterpret_cast<unsigned*>(h1s4 + (pair << 8));
#pragma unroll
    for (int k = 0; k < 8; ++k) {
        const unsigned pk = tp[k];
        const float ax = __uint_as_float(pk << 16);          // bf16 -> f32 exact
        const float ay = __uint_as_float(pk & 0xFFFF0000u);
        const float x0 = fmaf(ax, w1v.x, fmaf(ay, w1v.y, b1v.x));
        const float x1 = fmaf(ax, w1v.z, fmaf(ay, w1v.w, b1v.y));
        const int r = (half << 3) + k;   // row in pair tile; swizzle key = r&7 = k
        h1w[(r << 6) + ((((lane >> 2) ^ k) << 2) | (lane & 3))] = pack2(gelu_tanh(x0), gelu_tanh(x1));
    }
    __syncthreads();

    // --- B fragments from pair tile: col n = lane&15 (0..7 even, 8..15 odd) ---
    const uint4* h1b = h1s4 + (pair << 8);
    const int bslot = lane >> 4, bxor = lane & 7, brow = (lane & 15) * 16;
    bf16x8 bq0 = __builtin_bit_cast(bf16x8, h1b[brow + (( 0 + bslot) ^ bxor)]);
    bf16x8 bq1 = __builtin_bit_cast(bf16x8, h1b[brow + (( 4 + bslot) ^ bxor)]);
    bf16x8 bq2 = __builtin_bit_cast(bf16x8, h1b[brow + (( 8 + bslot) ^ bxor)]);
    bf16x8 bq3 = __builtin_bit_cast(bf16x8, h1b[brow + ((12 + bslot) ^ bxor)]);

    // weight for this lane's D column
    const float wsel = wts[(pair << 1) | ((lane >> 3) & 1)][lane & 7];

    // --- MFMA: this wave does f-tiles half*4 .. half*4+3 for BOTH rows ---
#pragma unroll 2
    for (int i = 0; i < 4; ++i) {
        const int ft = (half << 2) + i;
        const int arow = (ft * 16 + (lane & 15)) * 16;
        f32x4 acc = {0.f, 0.f, 0.f, 0.f};
        acc = __builtin_amdgcn_mfma_f32_16x16x32_bf16(
                  __builtin_bit_cast(bf16x8, w2s[arow + (( 0 + bslot) ^ bxor)]), bq0, acc, 0, 0, 0);
        acc = __builtin_amdgcn_mfma_f32_16x16x32_bf16(
                  __builtin_bit_cast(bf16x8, w2s[arow + (( 4 + bslot) ^ bxor)]), bq1, acc, 0, 0, 0);
        acc = __builtin_amdgcn_mfma_f32_16x16x32_bf16(
                  __builtin_bit_cast(bf16x8, w2s[arow + (( 8 + bslot) ^ bxor)]), bq2, acc, 0, 0, 0);
        acc = __builtin_amdgcn_mfma_f32_16x16x32_bf16(
                  __builtin_bit_cast(bf16x8, w2s[arow + ((12 + bslot) ^ bxor)]), bq3, acc, 0, 0, 0);

        // D: row f = ft*16 + (lane>>4)*4 + j, col = lane&15
        const float4 b2v = b2s4[ft * 4 + (lane >> 4)];
        float s0 = gelu_tanh(acc[0] + b2v.x) * wsel;
        float s1 = gelu_tanh(acc[1] + b2v.y) * wsel;
        float s2 = gelu_tanh(acc[2] + b2v.z) * wsel;
        float s3 = gelu_tanh(acc[3] + b2v.w) * wsel;
        // sum over the 8 k-slots (lanes sharing lane&~7) via DPP adds
        s0 = dpp_fadd<0xB1>(s0); s0 = dpp_fadd<0x4E>(s0); s0 = dpp_fadd<0x141>(s0);
        s1 = dpp_fadd<0xB1>(s1); s1 = dpp_fadd<0x4E>(s1); s1 = dpp_fadd<0x141>(s1);
        s2 = dpp_fadd<0xB1>(s2); s2 = dpp_fadd<0x4E>(s2); s2 = dpp_fadd<0x141>(s2);
        s3 = dpp_fadd<0xB1>(s3); s3 = dpp_fadd<0x4E>(s3); s3 = dpp_fadd<0x141>(s3);
        if ((lane & 7) == 0) {
            const int which = (lane >> 3) & 1;   // 0 = row even, 1 = row odd
            const size_t ob = (size_t)(rowbase + (pair << 1) + which) * NEMB
                              + ft * 16 + ((lane >> 4) << 2);
            *reinterpret_cast<float4*>(&out[ob]) = make_float4(s0, s1, s2, s3);
        }
    }
}

extern "C" void kernel_launch(void* const* d_in, const int* in_sizes, int n_in,
                              void* d_out, int out_size, void* d_ws, size_t ws_size,
                              hipStream_t stream)
{
    const float* Gl  = (const float*)d_in[0];
    const float* anc = (const float*)d_in[1];
    const float* W1  = (const float*)d_in[2];
    const float* b1  = (const float*)d_in[3];
    const float* W2  = (const float*)d_in[4];
    const float* b2  = (const float*)d_in[5];
    float* outp = (float*)d_out;

    fused_anchor_mlp<<<NB / 8, 512, 0, stream>>>(Gl, anc, W1, b1, W2, b2, outp);
}